// Round 15
// baseline (202.051 us; speedup 1.0000x reference)
//
#include <hip/hip_runtime.h>

#define B_  4
#define NT_ 1024
#define NS_ 1024
#define D_  1024
#define H_  16
#define HD_ 64

typedef unsigned short u16;
typedef __attribute__((ext_vector_type(8))) short short8;
typedef __attribute__((ext_vector_type(4))) float f32x4;
typedef __attribute__((ext_vector_type(4))) unsigned short u16x4;

static __device__ __forceinline__ u16 f2bf(float f) {
  unsigned u = __builtin_bit_cast(unsigned, f);
  u += 0x7fff + ((u >> 16) & 1);          // RNE
  return (u16)(u >> 16);
}

static __device__ __forceinline__ float bf2f(u16 h) {
  return __builtin_bit_cast(float, (unsigned)h << 16);
}

static __device__ __forceinline__ f32x4 mfma16(short8 a, short8 b, f32x4 c) {
  return __builtin_amdgcn_mfma_f32_16x16x32_bf16(a, b, c, 0, 0, 0);
}

// keep a loaded value alive in VGPRs (defeats load-sinking)
#define PIN(x) asm volatile("" : "+v"(x))

#define GLDS16(g, l) __builtin_amdgcn_global_load_lds( \
    (const __attribute__((address_space(1))) void*)(g), \
    (__attribute__((address_space(3))) void*)(l), 16, 0, 0)

// ---------------------------------------------------------------- convert (weights + mask)
struct CvtArgs {
  const float* src[5];
  u16* dst[5];
  int n[5];
};

__global__ __launch_bounds__(256) void cvt_kernel(CvtArgs a) {
  const int z = blockIdx.z;
  const float* __restrict__ src = a.src[z];
  u16* __restrict__ dst = a.dst[z];
  const int n = a.n[z];
  int i = (blockIdx.x * 256 + threadIdx.x) * 4;
  const int stride = gridDim.x * 256 * 4;
  for (; i < n; i += stride) {
    float4 v = *reinterpret_cast<const float4*>(src + i);
    u16x4 o;
    o[0] = f2bf(v.x); o[1] = f2bf(v.y); o[2] = f2bf(v.z); o[3] = f2bf(v.w);
    *reinterpret_cast<u16x4*>(dst + i) = o;
  }
}

// ---------------------------------------------------------------- GEMM (B^T form)
// C[i][j] = sum_k A[i][k]*Bt[j][k] + bias[j].  128x128 tile, BK=32, 4 waves.
// MODE: 0 = f32 row-major out, 1 = bf16 row-major out,
//       2 = bf16 transposed V out: row=(b,s), col=(h,hd) -> vpT[b][h][hd][s]
// AF32: A is f32 in global; reg-stage (f32x4 loads -> cvt -> ds_write) fuses
//       the conversion pass into the GEMM.  B always bf16 via global_load_lds.
template<int MODE, bool AF32>
static __device__ __forceinline__ void gemm_body(
    const void* __restrict__ Ain, const u16* __restrict__ Bt,
    const float* __restrict__ bias, void* __restrict__ Cout,
    const int N, const int K) {
  __shared__ u16 sA[128 * 32];
  __shared__ u16 sB[128 * 32];
  const int tid = threadIdx.x;
  const int wave = tid >> 6, lane = tid & 63;
  const int l15 = lane & 15, lq = lane >> 4;
  const size_t m0 = (size_t)blockIdx.y * 128;
  const size_t n0 = (size_t)blockIdx.x * 128;
  const int wr = (wave >> 1) * 64, wc = (wave & 1) * 64;
  f32x4 acc[4][4];
#pragma unroll
  for (int m = 0; m < 4; ++m)
#pragma unroll
    for (int n = 0; n < 4; ++n) acc[m][n] = (f32x4){0.f, 0.f, 0.f, 0.f};

  const int srow = lane >> 2;          // 0..15 within 16-row chunk
  const int scol = (lane & 3) * 8;     // 0,8,16,24

  for (int kt = 0; kt < K; kt += 32) {
#pragma unroll
    for (int i = 0; i < 2; ++i) {
      const int q = wave * 2 + i;      // 0..7 : 16-row chunk of the tile
      if (AF32) {
        const float* ga = (const float*)Ain + (m0 + q * 16 + srow) * K + kt + scol;
        float4 v0 = *reinterpret_cast<const float4*>(ga);
        float4 v1 = *reinterpret_cast<const float4*>(ga + 4);
        u16x4 p0, p1;
        p0[0] = f2bf(v0.x); p0[1] = f2bf(v0.y); p0[2] = f2bf(v0.z); p0[3] = f2bf(v0.w);
        p1[0] = f2bf(v1.x); p1[1] = f2bf(v1.y); p1[2] = f2bf(v1.z); p1[3] = f2bf(v1.w);
        u16* dst = sA + q * 512 + srow * 32 + scol;
        *reinterpret_cast<u16x4*>(dst) = p0;
        *reinterpret_cast<u16x4*>(dst + 4) = p1;
      } else {
        const u16* ga = (const u16*)Ain + (m0 + q * 16 + srow) * K + kt + scol;
        GLDS16(ga, sA + q * 512);
      }
      const u16* gb = Bt + (n0 + q * 16 + srow) * K + kt + scol;
      GLDS16(gb, sB + q * 512);
    }
    __syncthreads();                   // drains vmcnt (GLDS) + lgkm (ds_write)
    short8 af[4], bfr[4];
#pragma unroll
    for (int m = 0; m < 4; ++m)
      af[m] = *reinterpret_cast<const short8*>(sA + (wr + m * 16 + l15) * 32 + lq * 8);
#pragma unroll
    for (int n = 0; n < 4; ++n)
      bfr[n] = *reinterpret_cast<const short8*>(sB + (wc + n * 16 + l15) * 32 + lq * 8);
#pragma unroll
    for (int m = 0; m < 4; ++m)
#pragma unroll
      for (int n = 0; n < 4; ++n)
        acc[m][n] = mfma16(af[m], bfr[n], acc[m][n]);
    __syncthreads();
  }
  // epilogue: C/D layout col=lane&15, row=(lane>>4)*4+r
#pragma unroll
  for (int m = 0; m < 4; ++m) {
    const size_t row0 = m0 + wr + m * 16 + lq * 4;
#pragma unroll
    for (int n = 0; n < 4; ++n) {
      const size_t col = n0 + wc + n * 16 + l15;
      const float bv = bias[col];
      if (MODE == 2) {
        const int hh = (int)(col >> 6), hd = (int)(col & 63);
        const int bb = (int)(row0 >> 10), s0 = (int)(row0 & 1023);
        u16x4 o;
#pragma unroll
        for (int r = 0; r < 4; ++r) o[r] = f2bf(acc[m][n][r] + bv);
        *reinterpret_cast<u16x4*>(
            (u16*)Cout + (((size_t)(bb * H_ + hh) * HD_ + hd) << 10) + s0) = o;
      } else {
#pragma unroll
        for (int r = 0; r < 4; ++r) {
          const float v = acc[m][n][r] + bv;
          if (MODE == 1)
            ((u16*)Cout)[(row0 + r) * N + col] = f2bf(v);
          else
            ((float*)Cout)[(row0 + r) * N + col] = v;
        }
      }
    }
  }
}

__global__ __launch_bounds__(256) void qkv_gemm_kernel(
    const float* q, const float* k, const float* v,
    const u16* wq, const u16* wk, const u16* wv,
    const float* bq, const float* bk, const float* bv,
    u16* qp, u16* kp, u16* vpT) {
  const int z = blockIdx.z;
  if (z == 2) {
    gemm_body<2, true>(v, wv, bv, (void*)vpT, D_, D_);
  } else if (z == 1) {
    gemm_body<1, true>(k, wk, bk, (void*)kp, D_, D_);
  } else {
    gemm_body<1, true>(q, wq, bq, (void*)qp, D_, D_);
  }
}

__global__ __launch_bounds__(256) void oproj_kernel(
    const u16* __restrict__ A, const u16* __restrict__ Bt,
    const float* __restrict__ bias, float* __restrict__ C) {
  gemm_body<0, false>(A, Bt, bias, (void*)C, D_, D_);
}

// ---------------------------------------------------------------- fused attention
// 8-TASK PERSISTENT + TAIL BURST.  Key fix: __syncthreads drains vmcnt(0)
// (stores included, FIFO retirement) -> a store burst only overlaps work up
// to the NEXT barrier.  So: (a) wout burst moved to the task TAIL, where the
// next barrier (B1 of task it+1) is a full QK+exp phase away; (b) Pl/red are
// DOUBLE-BUFFERED so the tail burst of task it races nothing in task it+1;
// (c) next task's Q + mask are prefetched BEFORE the burst (FIFO: waiting on
// those loads tolerates the newer stores still being in flight); (d) mask is
// bf16 (halves the 262MB mask read stream).
__global__ __launch_bounds__(512, 2) void attn_kernel(
    const u16* __restrict__ qp, const u16* __restrict__ kp,
    const u16* __restrict__ vpT, const u16* __restrict__ mbf,
    float* __restrict__ wout, u16* __restrict__ ctx) {
  __shared__ u16 Pl[2][16 * 1024];     // 64 KB, XOR-swizzled bf16 P (unnorm)
  __shared__ float ctxp[16 * 64];      // 4 KB partial ctx (k-half 0)
  __shared__ float red[2][16 * 8];     // 1 KB row-sum partials
  __shared__ float rfin[16];

  const int h = blockIdx.y, b = blockIdx.z;
  const int tid = threadIdx.x, wave = tid >> 6, lane = tid & 63;
  const int l15 = lane & 15, lq = lane >> 4;
  const int wcb = wave * 128;
  const int kh = wave >> 2, dq = wave & 3;

  // ---- load + PIN all K fragments (A-operand): K[s=wcb+c*16+l15][d]
  const u16* kbase = kp + ((size_t)b * NS_) * D_ + h * HD_;
  short8 kf[8][2];
#pragma unroll
  for (int c = 0; c < 8; ++c)
#pragma unroll
    for (int ks = 0; ks < 2; ++ks)
      kf[c][ks] = *reinterpret_cast<const short8*>(
          kbase + (size_t)(wcb + c * 16 + l15) * D_ + ks * 32 + lq * 8);
#pragma unroll
  for (int c = 0; c < 8; ++c) { PIN(kf[c][0]); PIN(kf[c][1]); }

  // ---- load + PIN all V fragments for PV
  short8 vf[16];
  const u16* vbase = vpT + ((size_t)((b * H_ + h) * HD_ + dq * 16 + l15)) * NS_
                   + kh * 512 + lq * 8;
#pragma unroll
  for (int ks = 0; ks < 16; ++ks)
    vf[ks] = *reinterpret_cast<const short8*>(vbase + ks * 32);
#pragma unroll
  for (int ks = 0; ks < 16; ++ks) PIN(vf[ks]);

  const u16* qbase = qp + ((size_t)(b * NT_ + blockIdx.x * 128)) * D_ + h * HD_;
  const u16* mbb = mbf + wcb + lq * 4;             // + (qt*16+l15)*NS_

  // ---- prologue: Q + mask for task 0 (loop-carried registers)
  short8 qf[2];
  u16x4 mk[8];
  {
    const u16* qrow = qbase + (size_t)l15 * D_;
    qf[0] = *reinterpret_cast<const short8*>(qrow + lq * 8);
    qf[1] = *reinterpret_cast<const short8*>(qrow + 32 + lq * 8);
    const u16* mrow = mbb + (size_t)(blockIdx.x * 128 + l15) * NS_;
#pragma unroll
    for (int c = 0; c < 8; ++c)
      mk[c] = *reinterpret_cast<const u16x4*>(mrow + c * 16);
  }

  for (int it = 0; it < 8; ++it) {
    const int p = it & 1;
    const int qt = blockIdx.x * 8 + it;

    // QK^T from registers
    f32x4 acc[8];
#pragma unroll
    for (int c = 0; c < 8; ++c) acc[c] = (f32x4){0.f, 0.f, 0.f, 0.f};
#pragma unroll
    for (int c = 0; c < 8; ++c)
#pragma unroll
      for (int ks = 0; ks < 2; ++ks)
        acc[c] = mfma16(kf[c][ks], qf[ks], acc[c]);

    // fused: mask(bf16) + scale + exp -> unnormalized bf16 P + row-sum partial
    {
      const int t = l15;
      u16* prow = Pl[p] + t * 1024;
      const int swz = (t & 7) << 3;    // 16B-granule XOR in element units
      float s_part = 0.f;
#pragma unroll
      for (int c = 0; c < 8; ++c) {
        float e0 = __expf(acc[c][0] * 0.125f + bf2f(mk[c][0]));
        float e1 = __expf(acc[c][1] * 0.125f + bf2f(mk[c][1]));
        float e2 = __expf(acc[c][2] * 0.125f + bf2f(mk[c][2]));
        float e3 = __expf(acc[c][3] * 0.125f + bf2f(mk[c][3]));
        s_part += (e0 + e1) + (e2 + e3);
        u16x4 p4;
        p4[0] = f2bf(e0); p4[1] = f2bf(e1); p4[2] = f2bf(e2); p4[3] = f2bf(e3);
        *reinterpret_cast<u16x4*>(prow + ((wcb + c * 16 + lq * 4) ^ swz)) = p4;
      }
      s_part += __shfl_xor(s_part, 16);
      s_part += __shfl_xor(s_part, 32);
      if (lane < 16) red[p][l15 * 8 + wave] = s_part;
    }

    __syncthreads();                   // B1: P[p] + red[p] visible (drains tail burst of it-1)

    // rfin for ctx store (visible by B2)
    if (tid < 16) {
      float s = red[p][tid * 8];
#pragma unroll
      for (int w = 1; w < 8; ++w) s += red[p][tid * 8 + w];
      rfin[tid] = 1.0f / s;
    }

    // Phase B: ctx_unnorm[16][64] = P @ V.  wave -> (k-half, d-quarter)
    const u16* prow2 = Pl[p] + l15 * 1024;        // A-frag row t = l15
    const int swz2 = (l15 & 7) << 3;
    f32x4 acc2 = (f32x4){0.f, 0.f, 0.f, 0.f};
#pragma unroll
    for (int ks = 0; ks < 16; ++ks) {
      short8 pa = *reinterpret_cast<const short8*>(
          prow2 + ((kh * 512 + ks * 32 + lq * 8) ^ swz2));
      acc2 = mfma16(pa, vf[ks], acc2);
    }
    if (kh == 0) {
#pragma unroll
      for (int r = 0; r < 4; ++r)
        ctxp[(lq * 4 + r) * 64 + dq * 16 + l15] = acc2[r];
    }
    __syncthreads();                   // B2: rfin + ctxp visible

    // ctx store (normalized at write); rfin[lq*4+r] is a broadcast read
    if (kh == 1) {
      u16* cbase = ctx + ((size_t)(b * NT_ + qt * 16 + lq * 4)) * D_ + h * HD_ + dq * 16 + l15;
#pragma unroll
      for (int r = 0; r < 4; ++r) {
        const float v = (acc2[r] + ctxp[(lq * 4 + r) * 64 + dq * 16 + l15]) * rfin[lq * 4 + r];
        cbase[(size_t)r * D_] = f2bf(v);
      }
    }

    // PREFETCH next task's Q + mask BEFORE the store burst (FIFO vmcnt:
    // waits on these loads tolerate the newer stores still in flight)
    if (it < 7) {
      const u16* qrow = qbase + (size_t)((it + 1) * 16 + l15) * D_;
      qf[0] = *reinterpret_cast<const short8*>(qrow + lq * 8);
      qf[1] = *reinterpret_cast<const short8*>(qrow + 32 + lq * 8);
      const u16* mrow = mbb + (size_t)((blockIdx.x * 8 + it + 1) * 16 + l15) * NS_;
#pragma unroll
      for (int c = 0; c < 8; ++c)
        mk[c] = *reinterpret_cast<const u16x4*>(mrow + c * 16);
    }

    // TAIL wout burst from Pl[p]/red[p]: drains under next task's QK + exp
    // (window ends at B1 of task it+1).  Double-buffered Pl/red -> no race.
    {
      const int row = wave * 2 + (lane >> 5);
      float s = red[p][row * 8];
#pragma unroll
      for (int w = 1; w < 8; ++w) s += red[p][row * 8 + w];
      const float rinv = 1.0f / s;
      const int cb = (lane & 31) * 4;
      const u16* pr = Pl[p] + row * 1024;
      const int sw = (row & 7) << 3;
      float* wrow = wout + ((size_t)((b * H_ + h) * NT_ + qt * 16 + row)) * NS_;
#pragma unroll
      for (int ch = 0; ch < 8; ++ch) {
        const int e = ch * 128 + cb;
        u16x4 p4 = *reinterpret_cast<const u16x4*>(pr + (e ^ sw));
        f32x4 w4;
        w4[0] = bf2f(p4[0]) * rinv; w4[1] = bf2f(p4[1]) * rinv;
        w4[2] = bf2f(p4[2]) * rinv; w4[3] = bf2f(p4[3]) * rinv;
        __builtin_nontemporal_store(w4, reinterpret_cast<f32x4*>(wrow + e));
      }
    }
  }
}

// ---------------------------------------------------------------- launch
extern "C" void kernel_launch(void* const* d_in, const int* in_sizes, int n_in,
                              void* d_out, int out_size, void* d_ws, size_t ws_size,
                              hipStream_t stream) {
  const float* q   = (const float*)d_in[0];
  const float* k   = (const float*)d_in[1];
  const float* v   = (const float*)d_in[2];
  const float* q_w = (const float*)d_in[3];
  const float* k_w = (const float*)d_in[4];
  const float* v_w = (const float*)d_in[5];
  const float* o_w = (const float*)d_in[6];
  const float* b_q = (const float*)d_in[7];
  const float* b_k = (const float*)d_in[8];
  const float* b_v = (const float*)d_in[9];
  const float* b_o = (const float*)d_in[10];
  const float* msk = (const float*)d_in[11];

  float* out = (float*)d_out;                       // [B,NT,D]
  float* wout = out + (size_t)B_ * NT_ * D_;        // [B,H,NT,NS]

  // workspace layout (bf16 elements)
  u16* wq  = (u16*)d_ws;           // 1M  @0
  u16* wk  = wq + 1048576;         //     @2MB
  u16* wv  = wk + 1048576;         //     @4MB
  u16* wo  = wv + 1048576;         //     @6MB
  u16* qp  = wo + 1048576;         // 4M  @8MB
  u16* kp  = qp + 4194304;         //     @16MB
  u16* vpT = kp + 4194304;         //     @24MB  [B,H,HD,NS]
  u16* ctx = vpT + 4194304;        //     @32MB
  u16* mbf = ctx + 4194304;        // 1M  @40MB  bf16 mask (total 42MB)

  CvtArgs ca;
  ca.src[0] = q_w; ca.dst[0] = wq;  ca.n[0] = D_ * D_;
  ca.src[1] = k_w; ca.dst[1] = wk;  ca.n[1] = D_ * D_;
  ca.src[2] = v_w; ca.dst[2] = wv;  ca.n[2] = D_ * D_;
  ca.src[3] = o_w; ca.dst[3] = wo;  ca.n[3] = D_ * D_;
  ca.src[4] = msk; ca.dst[4] = mbf; ca.n[4] = NT_ * NS_;
  cvt_kernel<<<dim3(256, 1, 5), 256, 0, stream>>>(ca);

  qkv_gemm_kernel<<<dim3(8, 32, 3), 256, 0, stream>>>(
      q, k, v, wq, wk, wv, b_q, b_k, b_v, qp, kp, vpT);

  attn_kernel<<<dim3(8, 16, 4), 512, 0, stream>>>(qp, kp, vpT, mbf, wout, ctx);

  oproj_kernel<<<dim3(8, 32), 256, 0, stream>>>(ctx, wo, b_o, out);
}

// Round 16
// 196.364 us; speedup vs baseline: 1.0290x; 1.0290x over previous
//
#include <hip/hip_runtime.h>

#define B_  4
#define NT_ 1024
#define NS_ 1024
#define D_  1024
#define H_  16
#define HD_ 64

typedef unsigned short u16;
typedef __attribute__((ext_vector_type(8))) short short8;
typedef __attribute__((ext_vector_type(4))) float f32x4;
typedef __attribute__((ext_vector_type(4))) unsigned short u16x4;

static __device__ __forceinline__ u16 f2bf(float f) {
  unsigned u = __builtin_bit_cast(unsigned, f);
  u += 0x7fff + ((u >> 16) & 1);          // RNE
  return (u16)(u >> 16);
}

static __device__ __forceinline__ float bf2f(u16 h) {
  return __builtin_bit_cast(float, (unsigned)h << 16);
}

static __device__ __forceinline__ f32x4 mfma16(short8 a, short8 b, f32x4 c) {
  return __builtin_amdgcn_mfma_f32_16x16x32_bf16(a, b, c, 0, 0, 0);
}

// keep a loaded value alive in VGPRs (defeats load-sinking)
#define PIN(x) asm volatile("" : "+v"(x))

#define GLDS16(g, l) __builtin_amdgcn_global_load_lds( \
    (const __attribute__((address_space(1))) void*)(g), \
    (__attribute__((address_space(3))) void*)(l), 16, 0, 0)

// ---------------------------------------------------------------- convert (weights only)
struct CvtArgs {
  const float* src[4];
  u16* dst[4];
  int n[4];
};

__global__ __launch_bounds__(256) void cvt_kernel(CvtArgs a) {
  const int z = blockIdx.z;
  const float* __restrict__ src = a.src[z];
  u16* __restrict__ dst = a.dst[z];
  const int n = a.n[z];
  int i = (blockIdx.x * 256 + threadIdx.x) * 4;
  const int stride = gridDim.x * 256 * 4;
  for (; i < n; i += stride) {
    float4 v = *reinterpret_cast<const float4*>(src + i);
    u16x4 o;
    o[0] = f2bf(v.x); o[1] = f2bf(v.y); o[2] = f2bf(v.z); o[3] = f2bf(v.w);
    *reinterpret_cast<u16x4*>(dst + i) = o;
  }
}

// ---------------------------------------------------------------- GEMM (B^T form)
// C[i][j] = sum_k A[i][k]*Bt[j][k] + bias[j].  128x128 tile, BK=32, 4 waves.
// MODE: 0 = f32 row-major out, 1 = bf16 row-major out,
//       2 = bf16 transposed V out: row=(b,s), col=(h,hd) -> vpT[b][h][hd][s]
// AF32: A is f32 in global, SOFTWARE-PIPELINED: K-loop unrolled by 2 with two
//       named f32x4 register buffers (a0/a1) prefetched one K-step ahead and
//       PINned (load-sinking defeated).  Exposed latency per K-step becomes
//       max(A,B) instead of A-then-B.  B always bf16 via global_load_lds.
template<int MODE, bool AF32>
static __device__ __forceinline__ void gemm_body(
    const void* __restrict__ Ain, const u16* __restrict__ Bt,
    const float* __restrict__ bias, void* __restrict__ Cout,
    const int N, const int K) {
  __shared__ u16 sA[128 * 32];
  __shared__ u16 sB[128 * 32];
  const int tid = threadIdx.x;
  const int wave = tid >> 6, lane = tid & 63;
  const int l15 = lane & 15, lq = lane >> 4;
  const size_t m0 = (size_t)blockIdx.y * 128;
  const size_t n0 = (size_t)blockIdx.x * 128;
  const int wr = (wave >> 1) * 64, wc = (wave & 1) * 64;
  f32x4 acc[4][4];
#pragma unroll
  for (int m = 0; m < 4; ++m)
#pragma unroll
    for (int n = 0; n < 4; ++n) acc[m][n] = (f32x4){0.f, 0.f, 0.f, 0.f};

  const int srow = lane >> 2;          // 0..15 within 16-row chunk
  const int scol = (lane & 3) * 8;     // 0,8,16,24

  auto compute = [&]() {
    short8 af[4], bfr[4];
#pragma unroll
    for (int m = 0; m < 4; ++m)
      af[m] = *reinterpret_cast<const short8*>(sA + (wr + m * 16 + l15) * 32 + lq * 8);
#pragma unroll
    for (int n = 0; n < 4; ++n)
      bfr[n] = *reinterpret_cast<const short8*>(sB + (wc + n * 16 + l15) * 32 + lq * 8);
#pragma unroll
    for (int m = 0; m < 4; ++m)
#pragma unroll
      for (int n = 0; n < 4; ++n)
        acc[m][n] = mfma16(af[m], bfr[n], acc[m][n]);
  };

  if (AF32) {
    auto loadA = [&](f32x4 (&dst)[2][2], int ktv) {
#pragma unroll
      for (int i = 0; i < 2; ++i) {
        const float* ga = (const float*)Ain
            + (m0 + (wave * 2 + i) * 16 + srow) * K + ktv + scol;
        dst[i][0] = *reinterpret_cast<const f32x4*>(ga);
        dst[i][1] = *reinterpret_cast<const f32x4*>(ga + 4);
        PIN(dst[i][0]); PIN(dst[i][1]);
      }
    };
    auto storeA = [&](f32x4 (&src)[2][2]) {
#pragma unroll
      for (int i = 0; i < 2; ++i) {
        u16x4 p0, p1;
        p0[0] = f2bf(src[i][0][0]); p0[1] = f2bf(src[i][0][1]);
        p0[2] = f2bf(src[i][0][2]); p0[3] = f2bf(src[i][0][3]);
        p1[0] = f2bf(src[i][1][0]); p1[1] = f2bf(src[i][1][1]);
        p1[2] = f2bf(src[i][1][2]); p1[3] = f2bf(src[i][1][3]);
        u16* dst = sA + (wave * 2 + i) * 512 + srow * 32 + scol;
        *reinterpret_cast<u16x4*>(dst) = p0;
        *reinterpret_cast<u16x4*>(dst + 4) = p1;
      }
    };

    f32x4 a0[2][2], a1[2][2];
    loadA(a0, 0);
    for (int kt = 0; kt < K; kt += 64) {
      // ---- step 1: consume a0, prefetch a1 (kt+32 < K always: K % 64 == 0)
#pragma unroll
      for (int i = 0; i < 2; ++i) {
        const u16* gb = Bt + (n0 + (wave * 2 + i) * 16 + srow) * K + kt + scol;
        GLDS16(gb, sB + (wave * 2 + i) * 512);
      }
      storeA(a0);
      loadA(a1, kt + 32);
      __syncthreads();
      compute();
      __syncthreads();
      // ---- step 2: consume a1, prefetch a0 for next outer iteration
#pragma unroll
      for (int i = 0; i < 2; ++i) {
        const u16* gb = Bt + (n0 + (wave * 2 + i) * 16 + srow) * K + kt + 32 + scol;
        GLDS16(gb, sB + (wave * 2 + i) * 512);
      }
      storeA(a1);
      if (kt + 64 < K) loadA(a0, kt + 64);
      __syncthreads();
      compute();
      __syncthreads();
    }
  } else {
    for (int kt = 0; kt < K; kt += 32) {
#pragma unroll
      for (int i = 0; i < 2; ++i) {
        const int q = wave * 2 + i;
        const u16* ga = (const u16*)Ain + (m0 + q * 16 + srow) * K + kt + scol;
        GLDS16(ga, sA + q * 512);
        const u16* gb = Bt + (n0 + q * 16 + srow) * K + kt + scol;
        GLDS16(gb, sB + q * 512);
      }
      __syncthreads();
      compute();
      __syncthreads();
    }
  }

  // epilogue: C/D layout col=lane&15, row=(lane>>4)*4+r
#pragma unroll
  for (int m = 0; m < 4; ++m) {
    const size_t row0 = m0 + wr + m * 16 + lq * 4;
#pragma unroll
    for (int n = 0; n < 4; ++n) {
      const size_t col = n0 + wc + n * 16 + l15;
      const float bv = bias[col];
      if (MODE == 2) {
        const int hh = (int)(col >> 6), hd = (int)(col & 63);
        const int bb = (int)(row0 >> 10), s0 = (int)(row0 & 1023);
        u16x4 o;
#pragma unroll
        for (int r = 0; r < 4; ++r) o[r] = f2bf(acc[m][n][r] + bv);
        *reinterpret_cast<u16x4*>(
            (u16*)Cout + (((size_t)(bb * H_ + hh) * HD_ + hd) << 10) + s0) = o;
      } else {
#pragma unroll
        for (int r = 0; r < 4; ++r) {
          const float v = acc[m][n][r] + bv;
          if (MODE == 1)
            ((u16*)Cout)[(row0 + r) * N + col] = f2bf(v);
          else
            ((float*)Cout)[(row0 + r) * N + col] = v;
        }
      }
    }
  }
}

__global__ __launch_bounds__(256) void qkv_gemm_kernel(
    const float* q, const float* k, const float* v,
    const u16* wq, const u16* wk, const u16* wv,
    const float* bq, const float* bk, const float* bv,
    u16* qp, u16* kp, u16* vpT) {
  const int z = blockIdx.z;
  if (z == 2) {
    gemm_body<2, true>(v, wv, bv, (void*)vpT, D_, D_);
  } else if (z == 1) {
    gemm_body<1, true>(k, wk, bk, (void*)kp, D_, D_);
  } else {
    gemm_body<1, true>(q, wq, bq, (void*)qp, D_, D_);
  }
}

__global__ __launch_bounds__(256) void oproj_kernel(
    const u16* __restrict__ A, const u16* __restrict__ Bt,
    const float* __restrict__ bias, float* __restrict__ C) {
  gemm_body<0, false>(A, Bt, bias, (void*)C, D_, D_);
}

// ---------------------------------------------------------------- fused attention
// r14 version (best known, ~92us): 8-TASK PERSISTENT, grid (8,16,4) = 512
// blocks = exactly 2/CU, single residency round.  K/V fragments loaded once
// and PINNED in VGPRs; Q loaded per task.  Per task: QK -> exp -> P(LDS) ->
// B1 -> wout burst -> PV -> B2 -> ctx.
__global__ __launch_bounds__(512, 2) void attn_kernel(
    const u16* __restrict__ qp, const u16* __restrict__ kp,
    const u16* __restrict__ vpT, const float* __restrict__ mask,
    float* __restrict__ wout, u16* __restrict__ ctx) {
  __shared__ u16 Pl[16 * 1024];        // 32 KB, XOR-swizzled bf16 P (unnormalized)
  __shared__ float ctxp[16 * 64];      // 4 KB partial ctx (k-half 0)
  __shared__ float red[16 * 8];
  __shared__ float rfin[16];

  const int h = blockIdx.y, b = blockIdx.z;
  const int tid = threadIdx.x, wave = tid >> 6, lane = tid & 63;
  const int l15 = lane & 15, lq = lane >> 4;
  const int wcb = wave * 128;
  const int kh = wave >> 2, dq = wave & 3;

  // ---- load + PIN all K fragments (A-operand): K[s=wcb+c*16+l15][d]
  const u16* kbase = kp + ((size_t)b * NS_) * D_ + h * HD_;
  short8 kf[8][2];
#pragma unroll
  for (int c = 0; c < 8; ++c)
#pragma unroll
    for (int ks = 0; ks < 2; ++ks)
      kf[c][ks] = *reinterpret_cast<const short8*>(
          kbase + (size_t)(wcb + c * 16 + l15) * D_ + ks * 32 + lq * 8);
#pragma unroll
  for (int c = 0; c < 8; ++c) { PIN(kf[c][0]); PIN(kf[c][1]); }

  // ---- load + PIN all V fragments for PV
  short8 vf[16];
  const u16* vbase = vpT + ((size_t)((b * H_ + h) * HD_ + dq * 16 + l15)) * NS_
                   + kh * 512 + lq * 8;
#pragma unroll
  for (int ks = 0; ks < 16; ++ks)
    vf[ks] = *reinterpret_cast<const short8*>(vbase + ks * 32);
#pragma unroll
  for (int ks = 0; ks < 16; ++ks) PIN(vf[ks]);

  const u16* qbase = qp + ((size_t)(b * NT_ + blockIdx.x * 128)) * D_ + h * HD_;

  for (int it = 0; it < 8; ++it) {
    const int qt = blockIdx.x * 8 + it;

    // Q fragments for this task (latency hidden by co-resident block)
    short8 qf[2];
#pragma unroll
    for (int ks = 0; ks < 2; ++ks)
      qf[ks] = *reinterpret_cast<const short8*>(
          qbase + (size_t)(it * 16 + l15) * D_ + ks * 32 + lq * 8);

    // QK^T from registers
    f32x4 acc[8];
#pragma unroll
    for (int c = 0; c < 8; ++c) acc[c] = (f32x4){0.f, 0.f, 0.f, 0.f};
#pragma unroll
    for (int c = 0; c < 8; ++c)
#pragma unroll
      for (int ks = 0; ks < 2; ++ks)
        acc[c] = mfma16(kf[c][ks], qf[ks], acc[c]);

    // fused: mask + scale + exp -> unnormalized bf16 P (LDS) + row-sum partial
    const float* mbase = mask + (size_t)(qt * 16) * NS_ + wcb + lq * 4;
    {
      const int t = l15;
      u16* prow = Pl + t * 1024;
      const int swz = (t & 7) << 3;    // 16B-granule XOR in element units
      float s_part = 0.f;
#pragma unroll
      for (int c = 0; c < 8; ++c) {
        float4 mk = *reinterpret_cast<const float4*>(
            mbase + (size_t)l15 * NS_ + c * 16);
        float e0 = __expf(acc[c][0] * 0.125f + mk.x);
        float e1 = __expf(acc[c][1] * 0.125f + mk.y);
        float e2 = __expf(acc[c][2] * 0.125f + mk.z);
        float e3 = __expf(acc[c][3] * 0.125f + mk.w);
        s_part += (e0 + e1) + (e2 + e3);
        u16x4 p4;
        p4[0] = f2bf(e0); p4[1] = f2bf(e1); p4[2] = f2bf(e2); p4[3] = f2bf(e3);
        *reinterpret_cast<u16x4*>(prow + ((wcb + c * 16 + lq * 4) ^ swz)) = p4;
      }
      s_part += __shfl_xor(s_part, 16);
      s_part += __shfl_xor(s_part, 32);
      if (lane < 16) red[l15 * 8 + wave] = s_part;
    }

    __syncthreads();                   // B1: P + sum partials visible

    // rfin for ctx store (needs to be visible by B2)
    if (tid < 16) {
      float s = red[tid * 8];
#pragma unroll
      for (int w = 1; w < 8; ++w) s += red[tid * 8 + w];
      rfin[tid] = 1.0f / s;
    }

    // EARLY wout writeback: per-halfwave local row-sum from red[] partials,
    // coalesced nt stores; burst drains under PV + next task's QK/exp.
    {
      const int row = wave * 2 + (lane >> 5);
      float s = red[row * 8];
#pragma unroll
      for (int w = 1; w < 8; ++w) s += red[row * 8 + w];
      const float rinv = 1.0f / s;
      const int cb = (lane & 31) * 4;
      const u16* pr = Pl + row * 1024;
      const int sw = (row & 7) << 3;
      float* wrow = wout + ((size_t)((b * H_ + h) * NT_ + qt * 16 + row)) * NS_;
#pragma unroll
      for (int ch = 0; ch < 8; ++ch) {
        const int e = ch * 128 + cb;
        u16x4 p4 = *reinterpret_cast<const u16x4*>(pr + (e ^ sw));
        f32x4 w4;
        w4[0] = bf2f(p4[0]) * rinv; w4[1] = bf2f(p4[1]) * rinv;
        w4[2] = bf2f(p4[2]) * rinv; w4[3] = bf2f(p4[3]) * rinv;
        __builtin_nontemporal_store(w4, reinterpret_cast<f32x4*>(wrow + e));
      }
    }

    // Phase B: ctx_unnorm[16][64] = P @ V.  wave -> (k-half, d-quarter)
    const u16* prow2 = Pl + l15 * 1024;           // A-frag row t = l15
    const int swz2 = (l15 & 7) << 3;
    f32x4 acc2 = (f32x4){0.f, 0.f, 0.f, 0.f};
#pragma unroll
    for (int ks = 0; ks < 16; ++ks) {
      short8 pa = *reinterpret_cast<const short8*>(
          prow2 + ((kh * 512 + ks * 32 + lq * 8) ^ swz2));
      acc2 = mfma16(pa, vf[ks], acc2);
    }
    if (kh == 0) {
#pragma unroll
      for (int r = 0; r < 4; ++r)
        ctxp[(lq * 4 + r) * 64 + dq * 16 + l15] = acc2[r];
    }
    __syncthreads();                   // B2: rfin + ctxp visible; Pl/red free

    // ctx store (normalized at write).  rfin[lq*4+r] is a broadcast read.
    if (kh == 1) {
      u16* cbase = ctx + ((size_t)(b * NT_ + qt * 16 + lq * 4)) * D_ + h * HD_ + dq * 16 + l15;
#pragma unroll
      for (int r = 0; r < 4; ++r) {
        const float v = (acc2[r] + ctxp[(lq * 4 + r) * 64 + dq * 16 + l15]) * rfin[lq * 4 + r];
        cbase[(size_t)r * D_] = f2bf(v);
      }
    }
  }
}

// ---------------------------------------------------------------- launch
extern "C" void kernel_launch(void* const* d_in, const int* in_sizes, int n_in,
                              void* d_out, int out_size, void* d_ws, size_t ws_size,
                              hipStream_t stream) {
  const float* q   = (const float*)d_in[0];
  const float* k   = (const float*)d_in[1];
  const float* v   = (const float*)d_in[2];
  const float* q_w = (const float*)d_in[3];
  const float* k_w = (const float*)d_in[4];
  const float* v_w = (const float*)d_in[5];
  const float* o_w = (const float*)d_in[6];
  const float* b_q = (const float*)d_in[7];
  const float* b_k = (const float*)d_in[8];
  const float* b_v = (const float*)d_in[9];
  const float* b_o = (const float*)d_in[10];
  const float* msk = (const float*)d_in[11];

  float* out = (float*)d_out;                       // [B,NT,D]
  float* wout = out + (size_t)B_ * NT_ * D_;        // [B,H,NT,NS]

  // workspace layout (bf16 elements)
  u16* wq  = (u16*)d_ws;           // 1M  @0
  u16* wk  = wq + 1048576;         //     @2MB
  u16* wv  = wk + 1048576;         //     @4MB
  u16* wo  = wv + 1048576;         //     @6MB
  u16* qp  = wo + 1048576;         // 4M  @8MB
  u16* kp  = qp + 4194304;         //     @16MB
  u16* vpT = kp + 4194304;         //     @24MB  [B,H,HD,NS]
  u16* ctx = vpT + 4194304;        //     @32MB  (total 40MB)

  CvtArgs ca;
  ca.src[0] = q_w; ca.dst[0] = wq; ca.n[0] = D_ * D_;
  ca.src[1] = k_w; ca.dst[1] = wk; ca.n[1] = D_ * D_;
  ca.src[2] = v_w; ca.dst[2] = wv; ca.n[2] = D_ * D_;
  ca.src[3] = o_w; ca.dst[3] = wo; ca.n[3] = D_ * D_;
  cvt_kernel<<<dim3(256, 1, 4), 256, 0, stream>>>(ca);

  qkv_gemm_kernel<<<dim3(8, 32, 3), 256, 0, stream>>>(
      q, k, v, wq, wk, wv, b_q, b_k, b_v, qp, kp, vpT);

  attn_kernel<<<dim3(8, 16, 4), 512, 0, stream>>>(qp, kp, vpT, msk, wout, ctx);

  oproj_kernel<<<dim3(8, 32), 256, 0, stream>>>(ctx, wo, b_o, out);
}

// Round 17
// 175.698 us; speedup vs baseline: 1.1500x; 1.1176x over previous
//
#include <hip/hip_runtime.h>

#define B_  4
#define NT_ 1024
#define NS_ 1024
#define D_  1024
#define H_  16
#define HD_ 64

typedef unsigned short u16;
typedef __attribute__((ext_vector_type(8))) short short8;
typedef __attribute__((ext_vector_type(4))) float f32x4;
typedef __attribute__((ext_vector_type(4))) unsigned short u16x4;

static __device__ __forceinline__ u16 f2bf(float f) {
  unsigned u = __builtin_bit_cast(unsigned, f);
  u += 0x7fff + ((u >> 16) & 1);          // RNE
  return (u16)(u >> 16);
}

static __device__ __forceinline__ float bf2f(u16 h) {
  return __builtin_bit_cast(float, (unsigned)h << 16);
}

static __device__ __forceinline__ f32x4 mfma16(short8 a, short8 b, f32x4 c) {
  return __builtin_amdgcn_mfma_f32_16x16x32_bf16(a, b, c, 0, 0, 0);
}

// keep a loaded value alive in VGPRs (defeats load-sinking)
#define PIN(x) asm volatile("" : "+v"(x))

#define GLDS16(g, l) __builtin_amdgcn_global_load_lds( \
    (const __attribute__((address_space(1))) void*)(g), \
    (__attribute__((address_space(3))) void*)(l), 16, 0, 0)

// ---------------------------------------------------------------- convert
struct CvtArgs {
  const float* src[7];
  u16* dst[7];
  int n[7];
};

__global__ __launch_bounds__(256) void cvt_kernel(CvtArgs a) {
  const int z = blockIdx.z;
  const float* __restrict__ src = a.src[z];
  u16* __restrict__ dst = a.dst[z];
  const int n = a.n[z];
  int i = (blockIdx.x * 256 + threadIdx.x) * 4;
  const int stride = gridDim.x * 256 * 4;
  for (; i < n; i += stride) {
    float4 v = *reinterpret_cast<const float4*>(src + i);
    u16x4 o;
    o[0] = f2bf(v.x); o[1] = f2bf(v.y); o[2] = f2bf(v.z); o[3] = f2bf(v.w);
    *reinterpret_cast<u16x4*>(dst + i) = o;
  }
}

// ---------------------------------------------------------------- GEMM (B^T form)
// C[i][j] = sum_k A[i][k]*Bt[j][k] + bias[j].  128x128 tile, BK=32, 4 waves.
// Both operands staged via global_load_lds (the measured-fast path, r9).
// MODE: 0 = f32 row-major out, 1 = bf16 row-major out,
//       2 = bf16 transposed V out: row=(b,s), col=(h,hd) -> vpT[b][h][hd][s]
template<int MODE>
static __device__ __forceinline__ void gemm_body(
    const u16* __restrict__ A, const u16* __restrict__ Bt,
    const float* __restrict__ bias, void* __restrict__ Cout,
    const int N, const int K) {
  __shared__ u16 sA[128 * 32];
  __shared__ u16 sB[128 * 32];
  const int tid = threadIdx.x;
  const int wave = tid >> 6, lane = tid & 63;
  const int l15 = lane & 15, lq = lane >> 4;
  const size_t m0 = (size_t)blockIdx.y * 128;
  const size_t n0 = (size_t)blockIdx.x * 128;
  const int wr = (wave >> 1) * 64, wc = (wave & 1) * 64;
  f32x4 acc[4][4];
#pragma unroll
  for (int m = 0; m < 4; ++m)
#pragma unroll
    for (int n = 0; n < 4; ++n) acc[m][n] = (f32x4){0.f, 0.f, 0.f, 0.f};

  const int srow = lane >> 2;          // 0..15 within 16-row chunk
  const int scol = (lane & 3) * 8;     // 0,8,16,24

  for (int kt = 0; kt < K; kt += 32) {
#pragma unroll
    for (int i = 0; i < 2; ++i) {
      const int q = wave * 2 + i;      // 0..7 : 16-row chunk of the tile
      const u16* ga = A + (m0 + q * 16 + srow) * K + kt + scol;
      const u16* gb = Bt + (n0 + q * 16 + srow) * K + kt + scol;
      GLDS16(ga, sA + q * 512);
      GLDS16(gb, sB + q * 512);
    }
    __syncthreads();                   // drains vmcnt (global_load_lds) too
    short8 af[4], bfr[4];
#pragma unroll
    for (int m = 0; m < 4; ++m)
      af[m] = *reinterpret_cast<const short8*>(sA + (wr + m * 16 + l15) * 32 + lq * 8);
#pragma unroll
    for (int n = 0; n < 4; ++n)
      bfr[n] = *reinterpret_cast<const short8*>(sB + (wc + n * 16 + l15) * 32 + lq * 8);
#pragma unroll
    for (int m = 0; m < 4; ++m)
#pragma unroll
      for (int n = 0; n < 4; ++n)
        acc[m][n] = mfma16(af[m], bfr[n], acc[m][n]);
    __syncthreads();
  }
  // epilogue: C/D layout col=lane&15, row=(lane>>4)*4+r
#pragma unroll
  for (int m = 0; m < 4; ++m) {
    const size_t row0 = m0 + wr + m * 16 + lq * 4;
#pragma unroll
    for (int n = 0; n < 4; ++n) {
      const size_t col = n0 + wc + n * 16 + l15;
      const float bv = bias[col];
      if (MODE == 2) {
        const int hh = (int)(col >> 6), hd = (int)(col & 63);
        const int bb = (int)(row0 >> 10), s0 = (int)(row0 & 1023);
        u16x4 o;
#pragma unroll
        for (int r = 0; r < 4; ++r) o[r] = f2bf(acc[m][n][r] + bv);
        *reinterpret_cast<u16x4*>(
            (u16*)Cout + (((size_t)(bb * H_ + hh) * HD_ + hd) << 10) + s0) = o;
      } else {
#pragma unroll
        for (int r = 0; r < 4; ++r) {
          const float v = acc[m][n][r] + bv;
          if (MODE == 1)
            ((u16*)Cout)[(row0 + r) * N + col] = f2bf(v);
          else
            ((float*)Cout)[(row0 + r) * N + col] = v;
        }
      }
    }
  }
}

__global__ __launch_bounds__(256) void qkv_gemm_kernel(
    const u16* qb, const u16* kb, const u16* vb,
    const u16* wq, const u16* wk, const u16* wv,
    const float* bq, const float* bk, const float* bv,
    u16* qp, u16* kp, u16* vpT) {
  const int z = blockIdx.z;
  if (z == 2) {
    gemm_body<2>(vb, wv, bv, (void*)vpT, D_, D_);
  } else if (z == 1) {
    gemm_body<1>(kb, wk, bk, (void*)kp, D_, D_);
  } else {
    gemm_body<1>(qb, wq, bq, (void*)qp, D_, D_);
  }
}

__global__ __launch_bounds__(256) void oproj_kernel(
    const u16* __restrict__ A, const u16* __restrict__ Bt,
    const float* __restrict__ bias, float* __restrict__ C) {
  gemm_body<0>(A, Bt, bias, (void*)C, D_, D_);
}

// ---------------------------------------------------------------- fused attention
// r14 version (best known, ~92us): 8-TASK PERSISTENT, grid (8,16,4) = 512
// blocks = exactly 2/CU, single residency round.  K/V fragments loaded once
// and PINNED in VGPRs; Q loaded per task.  Per task: QK -> exp -> P(LDS) ->
// B1 -> wout burst -> PV -> B2 -> ctx.
__global__ __launch_bounds__(512, 2) void attn_kernel(
    const u16* __restrict__ qp, const u16* __restrict__ kp,
    const u16* __restrict__ vpT, const float* __restrict__ mask,
    float* __restrict__ wout, u16* __restrict__ ctx) {
  __shared__ u16 Pl[16 * 1024];        // 32 KB, XOR-swizzled bf16 P (unnormalized)
  __shared__ float ctxp[16 * 64];      // 4 KB partial ctx (k-half 0)
  __shared__ float red[16 * 8];
  __shared__ float rfin[16];

  const int h = blockIdx.y, b = blockIdx.z;
  const int tid = threadIdx.x, wave = tid >> 6, lane = tid & 63;
  const int l15 = lane & 15, lq = lane >> 4;
  const int wcb = wave * 128;
  const int kh = wave >> 2, dq = wave & 3;

  // ---- load + PIN all K fragments (A-operand): K[s=wcb+c*16+l15][d]
  const u16* kbase = kp + ((size_t)b * NS_) * D_ + h * HD_;
  short8 kf[8][2];
#pragma unroll
  for (int c = 0; c < 8; ++c)
#pragma unroll
    for (int ks = 0; ks < 2; ++ks)
      kf[c][ks] = *reinterpret_cast<const short8*>(
          kbase + (size_t)(wcb + c * 16 + l15) * D_ + ks * 32 + lq * 8);
#pragma unroll
  for (int c = 0; c < 8; ++c) { PIN(kf[c][0]); PIN(kf[c][1]); }

  // ---- load + PIN all V fragments for PV
  short8 vf[16];
  const u16* vbase = vpT + ((size_t)((b * H_ + h) * HD_ + dq * 16 + l15)) * NS_
                   + kh * 512 + lq * 8;
#pragma unroll
  for (int ks = 0; ks < 16; ++ks)
    vf[ks] = *reinterpret_cast<const short8*>(vbase + ks * 32);
#pragma unroll
  for (int ks = 0; ks < 16; ++ks) PIN(vf[ks]);

  const u16* qbase = qp + ((size_t)(b * NT_ + blockIdx.x * 128)) * D_ + h * HD_;

  for (int it = 0; it < 8; ++it) {
    const int qt = blockIdx.x * 8 + it;

    // Q fragments for this task (latency hidden by co-resident block)
    short8 qf[2];
#pragma unroll
    for (int ks = 0; ks < 2; ++ks)
      qf[ks] = *reinterpret_cast<const short8*>(
          qbase + (size_t)(it * 16 + l15) * D_ + ks * 32 + lq * 8);

    // QK^T from registers
    f32x4 acc[8];
#pragma unroll
    for (int c = 0; c < 8; ++c) acc[c] = (f32x4){0.f, 0.f, 0.f, 0.f};
#pragma unroll
    for (int c = 0; c < 8; ++c)
#pragma unroll
      for (int ks = 0; ks < 2; ++ks)
        acc[c] = mfma16(kf[c][ks], qf[ks], acc[c]);

    // fused: mask + scale + exp -> unnormalized bf16 P (LDS) + row-sum partial
    const float* mbase = mask + (size_t)(qt * 16) * NS_ + wcb + lq * 4;
    {
      const int t = l15;
      u16* prow = Pl + t * 1024;
      const int swz = (t & 7) << 3;    // 16B-granule XOR in element units
      float s_part = 0.f;
#pragma unroll
      for (int c = 0; c < 8; ++c) {
        float4 mk = *reinterpret_cast<const float4*>(
            mbase + (size_t)l15 * NS_ + c * 16);
        float e0 = __expf(acc[c][0] * 0.125f + mk.x);
        float e1 = __expf(acc[c][1] * 0.125f + mk.y);
        float e2 = __expf(acc[c][2] * 0.125f + mk.z);
        float e3 = __expf(acc[c][3] * 0.125f + mk.w);
        s_part += (e0 + e1) + (e2 + e3);
        u16x4 p4;
        p4[0] = f2bf(e0); p4[1] = f2bf(e1); p4[2] = f2bf(e2); p4[3] = f2bf(e3);
        *reinterpret_cast<u16x4*>(prow + ((wcb + c * 16 + lq * 4) ^ swz)) = p4;
      }
      s_part += __shfl_xor(s_part, 16);
      s_part += __shfl_xor(s_part, 32);
      if (lane < 16) red[l15 * 8 + wave] = s_part;
    }

    __syncthreads();                   // B1: P + sum partials visible

    // rfin for ctx store (needs to be visible by B2)
    if (tid < 16) {
      float s = red[tid * 8];
#pragma unroll
      for (int w = 1; w < 8; ++w) s += red[tid * 8 + w];
      rfin[tid] = 1.0f / s;
    }

    // EARLY wout writeback: per-halfwave local row-sum from red[] partials,
    // coalesced nt stores; burst drains under PV + next task's QK/exp.
    {
      const int row = wave * 2 + (lane >> 5);
      float s = red[row * 8];
#pragma unroll
      for (int w = 1; w < 8; ++w) s += red[row * 8 + w];
      const float rinv = 1.0f / s;
      const int cb = (lane & 31) * 4;
      const u16* pr = Pl + row * 1024;
      const int sw = (row & 7) << 3;
      float* wrow = wout + ((size_t)((b * H_ + h) * NT_ + qt * 16 + row)) * NS_;
#pragma unroll
      for (int ch = 0; ch < 8; ++ch) {
        const int e = ch * 128 + cb;
        u16x4 p4 = *reinterpret_cast<const u16x4*>(pr + (e ^ sw));
        f32x4 w4;
        w4[0] = bf2f(p4[0]) * rinv; w4[1] = bf2f(p4[1]) * rinv;
        w4[2] = bf2f(p4[2]) * rinv; w4[3] = bf2f(p4[3]) * rinv;
        __builtin_nontemporal_store(w4, reinterpret_cast<f32x4*>(wrow + e));
      }
    }

    // Phase B: ctx_unnorm[16][64] = P @ V.  wave -> (k-half, d-quarter)
    const u16* prow2 = Pl + l15 * 1024;           // A-frag row t = l15
    const int swz2 = (l15 & 7) << 3;
    f32x4 acc2 = (f32x4){0.f, 0.f, 0.f, 0.f};
#pragma unroll
    for (int ks = 0; ks < 16; ++ks) {
      short8 pa = *reinterpret_cast<const short8*>(
          prow2 + ((kh * 512 + ks * 32 + lq * 8) ^ swz2));
      acc2 = mfma16(pa, vf[ks], acc2);
    }
    if (kh == 0) {
#pragma unroll
      for (int r = 0; r < 4; ++r)
        ctxp[(lq * 4 + r) * 64 + dq * 16 + l15] = acc2[r];
    }
    __syncthreads();                   // B2: rfin + ctxp visible; Pl/red free

    // ctx store (normalized at write).  rfin[lq*4+r] is a broadcast read.
    if (kh == 1) {
      u16* cbase = ctx + ((size_t)(b * NT_ + qt * 16 + lq * 4)) * D_ + h * HD_ + dq * 16 + l15;
#pragma unroll
      for (int r = 0; r < 4; ++r) {
        const float v = (acc2[r] + ctxp[(lq * 4 + r) * 64 + dq * 16 + l15]) * rfin[lq * 4 + r];
        cbase[(size_t)r * D_] = f2bf(v);
      }
    }
  }
}

// ---------------------------------------------------------------- launch
extern "C" void kernel_launch(void* const* d_in, const int* in_sizes, int n_in,
                              void* d_out, int out_size, void* d_ws, size_t ws_size,
                              hipStream_t stream) {
  const float* q   = (const float*)d_in[0];
  const float* k   = (const float*)d_in[1];
  const float* v   = (const float*)d_in[2];
  const float* q_w = (const float*)d_in[3];
  const float* k_w = (const float*)d_in[4];
  const float* v_w = (const float*)d_in[5];
  const float* o_w = (const float*)d_in[6];
  const float* b_q = (const float*)d_in[7];
  const float* b_k = (const float*)d_in[8];
  const float* b_v = (const float*)d_in[9];
  const float* b_o = (const float*)d_in[10];
  const float* msk = (const float*)d_in[11];

  float* out = (float*)d_out;                       // [B,NT,D]
  float* wout = out + (size_t)B_ * NT_ * D_;        // [B,H,NT,NS]

  // workspace layout (bf16 elements)
  u16* qb  = (u16*)d_ws;           // 4M  @0
  u16* kb  = qb + 4194304;         //     @8MB
  u16* vb  = kb + 4194304;         //     @16MB
  u16* wq  = vb + 4194304;         // 1M  @24MB
  u16* wk  = wq + 1048576;         //     @26MB
  u16* wv  = wk + 1048576;         //     @28MB
  u16* wo  = wv + 1048576;         //     @30MB
  u16* qp  = wo + 1048576;         // 4M  @32MB
  u16* kp  = qp + 4194304;         //     @40MB
  u16* vpT = kp + 4194304;         //     @48MB  [B,H,HD,NS]  (total 56MB)
  u16* ctx = kb;                   // reuse: k bf16 dead after projections

  CvtArgs ca;
  ca.src[0] = q;   ca.dst[0] = qb; ca.n[0] = B_ * NT_ * D_;
  ca.src[1] = k;   ca.dst[1] = kb; ca.n[1] = B_ * NS_ * D_;
  ca.src[2] = v;   ca.dst[2] = vb; ca.n[2] = B_ * NS_ * D_;
  ca.src[3] = q_w; ca.dst[3] = wq; ca.n[3] = D_ * D_;
  ca.src[4] = k_w; ca.dst[4] = wk; ca.n[4] = D_ * D_;
  ca.src[5] = v_w; ca.dst[5] = wv; ca.n[5] = D_ * D_;
  ca.src[6] = o_w; ca.dst[6] = wo; ca.n[6] = D_ * D_;
  cvt_kernel<<<dim3(1024, 1, 7), 256, 0, stream>>>(ca);

  qkv_gemm_kernel<<<dim3(8, 32, 3), 256, 0, stream>>>(
      qb, kb, vb, wq, wk, wv, b_q, b_k, b_v, qp, kp, vpT);

  attn_kernel<<<dim3(8, 16, 4), 512, 0, stream>>>(qp, kp, vpT, msk, wout, ctx);

  oproj_kernel<<<dim3(8, 32), 256, 0, stream>>>(ctx, wo, b_o, out);
}

// Round 18
// 167.490 us; speedup vs baseline: 1.2063x; 1.0490x over previous
//
#include <hip/hip_runtime.h>

#define B_  4
#define NT_ 1024
#define NS_ 1024
#define D_  1024
#define H_  16
#define HD_ 64

typedef unsigned short u16;
typedef __attribute__((ext_vector_type(8))) short short8;
typedef __attribute__((ext_vector_type(4))) float f32x4;
typedef __attribute__((ext_vector_type(4))) unsigned short u16x4;

static __device__ __forceinline__ u16 f2bf(float f) {
  unsigned u = __builtin_bit_cast(unsigned, f);
  u += 0x7fff + ((u >> 16) & 1);          // RNE
  return (u16)(u >> 16);
}

static __device__ __forceinline__ float bf2f(u16 h) {
  return __builtin_bit_cast(float, (unsigned)h << 16);
}

static __device__ __forceinline__ f32x4 mfma16(short8 a, short8 b, f32x4 c) {
  return __builtin_amdgcn_mfma_f32_16x16x32_bf16(a, b, c, 0, 0, 0);
}

// keep a loaded value alive in VGPRs (defeats load-sinking)
#define PIN(x) asm volatile("" : "+v"(x))

#define GLDS16(g, l) __builtin_amdgcn_global_load_lds( \
    (const __attribute__((address_space(1))) void*)(g), \
    (__attribute__((address_space(3))) void*)(l), 16, 0, 0)

// ---------------------------------------------------------------- convert
struct CvtArgs {
  const float* src[7];
  u16* dst[7];
  int n[7];
};

__global__ __launch_bounds__(256) void cvt_kernel(CvtArgs a) {
  const int z = blockIdx.z;
  const float* __restrict__ src = a.src[z];
  u16* __restrict__ dst = a.dst[z];
  const int n = a.n[z];
  int i = (blockIdx.x * 256 + threadIdx.x) * 4;
  const int stride = gridDim.x * 256 * 4;
  for (; i < n; i += stride) {
    float4 v = *reinterpret_cast<const float4*>(src + i);
    u16x4 o;
    o[0] = f2bf(v.x); o[1] = f2bf(v.y); o[2] = f2bf(v.z); o[3] = f2bf(v.w);
    *reinterpret_cast<u16x4*>(dst + i) = o;
  }
}

// ---------------------------------------------------------------- GEMM (B^T form)
// C[i][j] = sum_k A[i][k]*Bt[j][k] + bias[j].  128x128 tile, BK=64, 4 waves.
// 32 MFMA per barrier pair (was 16 at BK=32) -> half the barriers, same bytes.
// LDS chunk layout: s[q][half][srow][32], q = 16-row chunk, half = 32-col half.
// MODE: 0 = f32 row-major out, 1 = bf16 row-major out,
//       2 = bf16 transposed V out: row=(b,s), col=(h,hd) -> vpT[b][h][hd][s]
template<int MODE>
static __device__ __forceinline__ void gemm_body(
    const u16* __restrict__ A, const u16* __restrict__ Bt,
    const float* __restrict__ bias, void* __restrict__ Cout,
    const int N, const int K) {
  __shared__ u16 sA[128 * 64];
  __shared__ u16 sB[128 * 64];
  const int tid = threadIdx.x;
  const int wave = tid >> 6, lane = tid & 63;
  const int l15 = lane & 15, lq = lane >> 4;
  const size_t m0 = (size_t)blockIdx.y * 128;
  const size_t n0 = (size_t)blockIdx.x * 128;
  const int wr = (wave >> 1) * 64, wc = (wave & 1) * 64;
  f32x4 acc[4][4];
#pragma unroll
  for (int m = 0; m < 4; ++m)
#pragma unroll
    for (int n = 0; n < 4; ++n) acc[m][n] = (f32x4){0.f, 0.f, 0.f, 0.f};

  const int srow = lane >> 2;          // 0..15 within 16-row chunk
  const int scol = (lane & 3) * 8;     // 0,8,16,24

  for (int kt = 0; kt < K; kt += 64) {
#pragma unroll
    for (int i = 0; i < 2; ++i) {
      const int q = wave * 2 + i;      // 0..7 : 16-row chunk of the tile
#pragma unroll
      for (int hf = 0; hf < 2; ++hf) {
        const u16* ga = A + (m0 + q * 16 + srow) * K + kt + hf * 32 + scol;
        const u16* gb = Bt + (n0 + q * 16 + srow) * K + kt + hf * 32 + scol;
        GLDS16(ga, sA + q * 1024 + hf * 512);
        GLDS16(gb, sB + q * 1024 + hf * 512);
      }
    }
    __syncthreads();                   // drains vmcnt (global_load_lds) too
    short8 af[4][2], bfr[4][2];
#pragma unroll
    for (int m = 0; m < 4; ++m)
#pragma unroll
      for (int ks = 0; ks < 2; ++ks)
        af[m][ks] = *reinterpret_cast<const short8*>(
            sA + ((wr >> 4) + m) * 1024 + ks * 512 + l15 * 32 + lq * 8);
#pragma unroll
    for (int n = 0; n < 4; ++n)
#pragma unroll
      for (int ks = 0; ks < 2; ++ks)
        bfr[n][ks] = *reinterpret_cast<const short8*>(
            sB + ((wc >> 4) + n) * 1024 + ks * 512 + l15 * 32 + lq * 8);
#pragma unroll
    for (int m = 0; m < 4; ++m)
#pragma unroll
      for (int n = 0; n < 4; ++n)
#pragma unroll
        for (int ks = 0; ks < 2; ++ks)
          acc[m][n] = mfma16(af[m][ks], bfr[n][ks], acc[m][n]);
    __syncthreads();
  }
  // epilogue: C/D layout col=lane&15, row=(lane>>4)*4+r
#pragma unroll
  for (int m = 0; m < 4; ++m) {
    const size_t row0 = m0 + wr + m * 16 + lq * 4;
#pragma unroll
    for (int n = 0; n < 4; ++n) {
      const size_t col = n0 + wc + n * 16 + l15;
      const float bv = bias[col];
      if (MODE == 2) {
        const int hh = (int)(col >> 6), hd = (int)(col & 63);
        const int bb = (int)(row0 >> 10), s0 = (int)(row0 & 1023);
        u16x4 o;
#pragma unroll
        for (int r = 0; r < 4; ++r) o[r] = f2bf(acc[m][n][r] + bv);
        *reinterpret_cast<u16x4*>(
            (u16*)Cout + (((size_t)(bb * H_ + hh) * HD_ + hd) << 10) + s0) = o;
      } else {
#pragma unroll
        for (int r = 0; r < 4; ++r) {
          const float v = acc[m][n][r] + bv;
          if (MODE == 1)
            ((u16*)Cout)[(row0 + r) * N + col] = f2bf(v);
          else
            ((float*)Cout)[(row0 + r) * N + col] = v;
        }
      }
    }
  }
}

__global__ __launch_bounds__(256) void qkv_gemm_kernel(
    const u16* qb, const u16* kb, const u16* vb,
    const u16* wq, const u16* wk, const u16* wv,
    const float* bq, const float* bk, const float* bv,
    u16* qp, u16* kp, u16* vpT) {
  const int z = blockIdx.z;
  if (z == 2) {
    gemm_body<2>(vb, wv, bv, (void*)vpT, D_, D_);
  } else if (z == 1) {
    gemm_body<1>(kb, wk, bk, (void*)kp, D_, D_);
  } else {
    gemm_body<1>(qb, wq, bq, (void*)qp, D_, D_);
  }
}

__global__ __launch_bounds__(256) void oproj_kernel(
    const u16* __restrict__ A, const u16* __restrict__ Bt,
    const float* __restrict__ bias, float* __restrict__ C) {
  gemm_body<0>(A, Bt, bias, (void*)C, D_, D_);
}

// ---------------------------------------------------------------- fused attention
// r14 version (best known, ~92us): 8-TASK PERSISTENT, grid (8,16,4) = 512
// blocks = exactly 2/CU, single residency round.  K/V fragments loaded once
// and PINNED in VGPRs; Q loaded per task.  Per task: QK -> exp -> P(LDS) ->
// B1 -> wout burst -> PV -> B2 -> ctx.
__global__ __launch_bounds__(512, 2) void attn_kernel(
    const u16* __restrict__ qp, const u16* __restrict__ kp,
    const u16* __restrict__ vpT, const float* __restrict__ mask,
    float* __restrict__ wout, u16* __restrict__ ctx) {
  __shared__ u16 Pl[16 * 1024];        // 32 KB, XOR-swizzled bf16 P (unnormalized)
  __shared__ float ctxp[16 * 64];      // 4 KB partial ctx (k-half 0)
  __shared__ float red[16 * 8];
  __shared__ float rfin[16];

  const int h = blockIdx.y, b = blockIdx.z;
  const int tid = threadIdx.x, wave = tid >> 6, lane = tid & 63;
  const int l15 = lane & 15, lq = lane >> 4;
  const int wcb = wave * 128;
  const int kh = wave >> 2, dq = wave & 3;

  // ---- load + PIN all K fragments (A-operand): K[s=wcb+c*16+l15][d]
  const u16* kbase = kp + ((size_t)b * NS_) * D_ + h * HD_;
  short8 kf[8][2];
#pragma unroll
  for (int c = 0; c < 8; ++c)
#pragma unroll
    for (int ks = 0; ks < 2; ++ks)
      kf[c][ks] = *reinterpret_cast<const short8*>(
          kbase + (size_t)(wcb + c * 16 + l15) * D_ + ks * 32 + lq * 8);
#pragma unroll
  for (int c = 0; c < 8; ++c) { PIN(kf[c][0]); PIN(kf[c][1]); }

  // ---- load + PIN all V fragments for PV
  short8 vf[16];
  const u16* vbase = vpT + ((size_t)((b * H_ + h) * HD_ + dq * 16 + l15)) * NS_
                   + kh * 512 + lq * 8;
#pragma unroll
  for (int ks = 0; ks < 16; ++ks)
    vf[ks] = *reinterpret_cast<const short8*>(vbase + ks * 32);
#pragma unroll
  for (int ks = 0; ks < 16; ++ks) PIN(vf[ks]);

  const u16* qbase = qp + ((size_t)(b * NT_ + blockIdx.x * 128)) * D_ + h * HD_;

  for (int it = 0; it < 8; ++it) {
    const int qt = blockIdx.x * 8 + it;

    // Q fragments for this task (latency hidden by co-resident block)
    short8 qf[2];
#pragma unroll
    for (int ks = 0; ks < 2; ++ks)
      qf[ks] = *reinterpret_cast<const short8*>(
          qbase + (size_t)(it * 16 + l15) * D_ + ks * 32 + lq * 8);

    // QK^T from registers
    f32x4 acc[8];
#pragma unroll
    for (int c = 0; c < 8; ++c) acc[c] = (f32x4){0.f, 0.f, 0.f, 0.f};
#pragma unroll
    for (int c = 0; c < 8; ++c)
#pragma unroll
      for (int ks = 0; ks < 2; ++ks)
        acc[c] = mfma16(kf[c][ks], qf[ks], acc[c]);

    // fused: mask + scale + exp -> unnormalized bf16 P (LDS) + row-sum partial
    const float* mbase = mask + (size_t)(qt * 16) * NS_ + wcb + lq * 4;
    {
      const int t = l15;
      u16* prow = Pl + t * 1024;
      const int swz = (t & 7) << 3;    // 16B-granule XOR in element units
      float s_part = 0.f;
#pragma unroll
      for (int c = 0; c < 8; ++c) {
        float4 mk = *reinterpret_cast<const float4*>(
            mbase + (size_t)l15 * NS_ + c * 16);
        float e0 = __expf(acc[c][0] * 0.125f + mk.x);
        float e1 = __expf(acc[c][1] * 0.125f + mk.y);
        float e2 = __expf(acc[c][2] * 0.125f + mk.z);
        float e3 = __expf(acc[c][3] * 0.125f + mk.w);
        s_part += (e0 + e1) + (e2 + e3);
        u16x4 p4;
        p4[0] = f2bf(e0); p4[1] = f2bf(e1); p4[2] = f2bf(e2); p4[3] = f2bf(e3);
        *reinterpret_cast<u16x4*>(prow + ((wcb + c * 16 + lq * 4) ^ swz)) = p4;
      }
      s_part += __shfl_xor(s_part, 16);
      s_part += __shfl_xor(s_part, 32);
      if (lane < 16) red[l15 * 8 + wave] = s_part;
    }

    __syncthreads();                   // B1: P + sum partials visible

    // rfin for ctx store (needs to be visible by B2)
    if (tid < 16) {
      float s = red[tid * 8];
#pragma unroll
      for (int w = 1; w < 8; ++w) s += red[tid * 8 + w];
      rfin[tid] = 1.0f / s;
    }

    // EARLY wout writeback: per-halfwave local row-sum from red[] partials,
    // coalesced nt stores; burst drains under PV + next task's QK/exp.
    {
      const int row = wave * 2 + (lane >> 5);
      float s = red[row * 8];
#pragma unroll
      for (int w = 1; w < 8; ++w) s += red[row * 8 + w];
      const float rinv = 1.0f / s;
      const int cb = (lane & 31) * 4;
      const u16* pr = Pl + row * 1024;
      const int sw = (row & 7) << 3;
      float* wrow = wout + ((size_t)((b * H_ + h) * NT_ + qt * 16 + row)) * NS_;
#pragma unroll
      for (int ch = 0; ch < 8; ++ch) {
        const int e = ch * 128 + cb;
        u16x4 p4 = *reinterpret_cast<const u16x4*>(pr + (e ^ sw));
        f32x4 w4;
        w4[0] = bf2f(p4[0]) * rinv; w4[1] = bf2f(p4[1]) * rinv;
        w4[2] = bf2f(p4[2]) * rinv; w4[3] = bf2f(p4[3]) * rinv;
        __builtin_nontemporal_store(w4, reinterpret_cast<f32x4*>(wrow + e));
      }
    }

    // Phase B: ctx_unnorm[16][64] = P @ V.  wave -> (k-half, d-quarter)
    const u16* prow2 = Pl + l15 * 1024;           // A-frag row t = l15
    const int swz2 = (l15 & 7) << 3;
    f32x4 acc2 = (f32x4){0.f, 0.f, 0.f, 0.f};
#pragma unroll
    for (int ks = 0; ks < 16; ++ks) {
      short8 pa = *reinterpret_cast<const short8*>(
          prow2 + ((kh * 512 + ks * 32 + lq * 8) ^ swz2));
      acc2 = mfma16(pa, vf[ks], acc2);
    }
    if (kh == 0) {
#pragma unroll
      for (int r = 0; r < 4; ++r)
        ctxp[(lq * 4 + r) * 64 + dq * 16 + l15] = acc2[r];
    }
    __syncthreads();                   // B2: rfin + ctxp visible; Pl/red free

    // ctx store (normalized at write).  rfin[lq*4+r] is a broadcast read.
    if (kh == 1) {
      u16* cbase = ctx + ((size_t)(b * NT_ + qt * 16 + lq * 4)) * D_ + h * HD_ + dq * 16 + l15;
#pragma unroll
      for (int r = 0; r < 4; ++r) {
        const float v = (acc2[r] + ctxp[(lq * 4 + r) * 64 + dq * 16 + l15]) * rfin[lq * 4 + r];
        cbase[(size_t)r * D_] = f2bf(v);
      }
    }
  }
}

// ---------------------------------------------------------------- launch
extern "C" void kernel_launch(void* const* d_in, const int* in_sizes, int n_in,
                              void* d_out, int out_size, void* d_ws, size_t ws_size,
                              hipStream_t stream) {
  const float* q   = (const float*)d_in[0];
  const float* k   = (const float*)d_in[1];
  const float* v   = (const float*)d_in[2];
  const float* q_w = (const float*)d_in[3];
  const float* k_w = (const float*)d_in[4];
  const float* v_w = (const float*)d_in[5];
  const float* o_w = (const float*)d_in[6];
  const float* b_q = (const float*)d_in[7];
  const float* b_k = (const float*)d_in[8];
  const float* b_v = (const float*)d_in[9];
  const float* b_o = (const float*)d_in[10];
  const float* msk = (const float*)d_in[11];

  float* out = (float*)d_out;                       // [B,NT,D]
  float* wout = out + (size_t)B_ * NT_ * D_;        // [B,H,NT,NS]

  // workspace layout (bf16 elements)
  u16* qb  = (u16*)d_ws;           // 4M  @0
  u16* kb  = qb + 4194304;         //     @8MB
  u16* vb  = kb + 4194304;         //     @16MB
  u16* wq  = vb + 4194304;         // 1M  @24MB
  u16* wk  = wq + 1048576;         //     @26MB
  u16* wv  = wk + 1048576;         //     @28MB
  u16* wo  = wv + 1048576;         //     @30MB
  u16* qp  = wo + 1048576;         // 4M  @32MB
  u16* kp  = qp + 4194304;         //     @40MB
  u16* vpT = kp + 4194304;         //     @48MB  [B,H,HD,NS]  (total 56MB)
  u16* ctx = kb;                   // reuse: k bf16 dead after projections

  CvtArgs ca;
  ca.src[0] = q;   ca.dst[0] = qb; ca.n[0] = B_ * NT_ * D_;
  ca.src[1] = k;   ca.dst[1] = kb; ca.n[1] = B_ * NS_ * D_;
  ca.src[2] = v;   ca.dst[2] = vb; ca.n[2] = B_ * NS_ * D_;
  ca.src[3] = q_w; ca.dst[3] = wq; ca.n[3] = D_ * D_;
  ca.src[4] = k_w; ca.dst[4] = wk; ca.n[4] = D_ * D_;
  ca.src[5] = v_w; ca.dst[5] = wv; ca.n[5] = D_ * D_;
  ca.src[6] = o_w; ca.dst[6] = wo; ca.n[6] = D_ * D_;
  cvt_kernel<<<dim3(1024, 1, 7), 256, 0, stream>>>(ca);

  qkv_gemm_kernel<<<dim3(8, 32, 3), 256, 0, stream>>>(
      qb, kb, vb, wq, wk, wv, b_q, b_k, b_v, qp, kp, vpT);

  attn_kernel<<<dim3(8, 16, 4), 512, 0, stream>>>(qp, kp, vpT, msk, wout, ctx);

  oproj_kernel<<<dim3(8, 32), 256, 0, stream>>>(ctx, wo, b_o, out);
}